// Round 6
// baseline (2610.451 us; speedup 1.0000x reference)
//
#include <hip/hip_runtime.h>
#include <stdint.h>

#define GAS __attribute__((address_space(1)))
#define LAS __attribute__((address_space(3)))

typedef __attribute__((ext_vector_type(8))) short bf16x8;
typedef __attribute__((ext_vector_type(4))) float f32x4;

static constexpr int NB = 8192;    // batch
static constexpr int DD = 768;     // model dim (K)
static constexpr int FF = 32768;   // latent dim (N)
static constexpr int TK = 32;      // top-k
static constexpr int RUNC = 64;    // refined candidate cap per row
static constexpr int CAP = 1024;   // raw survivor cap per row
static constexpr int NS2 = 256;    // partial-sum slots for mean(W^2)
static constexpr int FC = 8192;    // F-chunk (B-chunk 12.6 MB -> L2/L3 resident)

__device__ __forceinline__ ushort f2bf(float f) {
    unsigned x = __float_as_uint(f);
    unsigned r = (x + 0x7FFFu + ((x >> 16) & 1u)) >> 16;
    return (ushort)r;
}
__device__ __forceinline__ ushort sortkey(ushort u) {
    return (u & 0x8000u) ? (ushort)(u ^ 0xFFFFu) : (ushort)(u | 0x8000u);
}
__device__ __forceinline__ float bf2f(ushort u) {
    return __uint_as_float(((unsigned)u) << 16);
}
__device__ __forceinline__ void gload_lds16(const void* g, void* l) {
    __builtin_amdgcn_global_load_lds((const GAS unsigned int*)g,
                                     (LAS unsigned int*)l, 16, 0, 0);
}

// ---------------- prep: x_bf16 = bf16(x - pre_bias) ----------------
__global__ __launch_bounds__(256) void prep_x_k(const float* __restrict__ x,
                                                const float* __restrict__ pb,
                                                ushort* __restrict__ x16) {
    const int n4 = NB * DD / 4;
    for (int i = blockIdx.x * 256 + threadIdx.x; i < n4; i += gridDim.x * 256) {
        float4 v = ((const float4*)x)[i];
        float4 p = ((const float4*)pb)[i % (DD / 4)];
        ushort4 o;
        o.x = f2bf(v.x - p.x); o.y = f2bf(v.y - p.y);
        o.z = f2bf(v.z - p.z); o.w = f2bf(v.w - p.w);
        ((ushort4*)x16)[i] = o;
    }
}

// ------------- prep: transpose W_enc [D,F] -> Wt [F,D] (bf16 + f32) + sum(W^2) -------------
__global__ __launch_bounds__(256) void prep_w_k(const float* __restrict__ W,
                                                ushort* __restrict__ Wt16,
                                                float* __restrict__ Wt32,
                                                float* __restrict__ s2part) {
    __shared__ float tile[32][33];
    int f0 = blockIdx.x * 32, d0 = blockIdx.y * 32;
    int tx = threadIdx.x & 31, ty = threadIdx.x >> 5;  // ty 0..7
    float ss = 0.f;
#pragma unroll
    for (int q = 0; q < 4; q++) {
        int dl = ty + q * 8;
        float v = W[(size_t)(d0 + dl) * FF + f0 + tx];
        tile[dl][tx] = v;
        ss += v * v;
    }
#pragma unroll
    for (int o = 32; o >= 1; o >>= 1) ss += __shfl_down(ss, o);
    if ((threadIdx.x & 63) == 0) {
        int slot = (blockIdx.x * 97 + blockIdx.y * 13 + (threadIdx.x >> 6)) & (NS2 - 1);
        atomicAdd(&s2part[slot], ss);
    }
    __syncthreads();
#pragma unroll
    for (int q = 0; q < 4; q++) {
        int fl = ty + q * 8;
        float v = tile[tx][fl];
        size_t o = (size_t)(f0 + fl) * DD + d0 + tx;
        Wt16[o] = f2bf(v);
        if (Wt32) Wt32[o] = v;
    }
}

// ---------------- per-row threshold: tau[b] = 2.25 * sqrt(mean(W^2)) * ||x_b - pb|| ----------------
__global__ __launch_bounds__(256) void rn_k(const float* __restrict__ x,
                                            const float* __restrict__ pb,
                                            const float* __restrict__ s2part,
                                            float* __restrict__ tau) {
    int t = threadIdx.x, l = t & 63, w = t >> 6;
    __shared__ float wsum[4];
    __shared__ float s2m;
    float p = s2part[t];  // NS2 == 256
#pragma unroll
    for (int o = 32; o >= 1; o >>= 1) p += __shfl_down(p, o);
    if (l == 0) wsum[w] = p;
    __syncthreads();
    if (t == 0) s2m = (wsum[0] + wsum[1] + wsum[2] + wsum[3]) / ((float)DD * (float)FF);
    __syncthreads();
    int row = blockIdx.x * 4 + w;
    float ss = 0.f;
#pragma unroll
    for (int q = 0; q < 12; q++) {
        int d = l + 64 * q;
        float v = x[(size_t)row * DD + d] - pb[d];
        ss += v * v;
    }
#pragma unroll
    for (int o = 32; o >= 1; o >>= 1) ss += __shfl_down(ss, o);
    if (l == 0) tau[row] = 2.25f * sqrtf(s2m * ss);
}

// ---------------- bf16 MFMA GEMM with fused threshold filter, F-chunked for B residency ----------------
// 128x128 tile, BK=64, 4 waves (2x2), each wave 64x64 via 4x4 frags of 16x16x32.
// Epilogue: v = acc + lbias; if v >= tau[row], append (key<<16 | (32767-f)) to cand[row].
__global__ __launch_bounds__(256) void gemm_k(const ushort* __restrict__ A,
                                              const ushort* __restrict__ Bt,
                                              const float* __restrict__ lbias,
                                              const float* __restrict__ tau,
                                              unsigned* __restrict__ cand,
                                              unsigned* __restrict__ ccnt,
                                              int f0, int Fcn) {
    __shared__ __align__(16) char smem[32768];
    char* As = smem;
    char* Bs = smem + 16384;

    int ntil = Fcn >> 7;                     // 64
    int nwg = (NB / 128) * ntil;             // 4096, %8==0
    int cpx = nwg >> 3;
    int bid = (int)blockIdx.x;
    int wg = (bid & 7) * cpx + (bid >> 3);   // bijective XCD swizzle
    int mt = wg / ntil, nt = wg % ntil;
    int m0 = mt << 7, n0l = nt << 7;

    int t = threadIdx.x, l = t & 63;
    int w = t >> 6, wm = w >> 1, wn = w & 1;

    int rs = t >> 3, cs = t & 7;
    const ushort* ga = A + (size_t)(m0 + rs) * DD + cs * 8;
    const ushort* gb = Bt + (size_t)(f0 + n0l + rs) * DD + cs * 8;
    char* lA = As + t * 16;
    char* lB = Bs + t * 16;

    f32x4 acc[4][4] = {};
    int k0b = (l >> 4) << 4;

    for (int kt = 0; kt < DD; kt += 64) {
#pragma unroll
        for (int i = 0; i < 4; i++) {
            gload_lds16(ga + kt + (size_t)(i * 32) * DD, lA + i * 4096);
            gload_lds16(gb + kt + (size_t)(i * 32) * DD, lB + i * 4096);
        }
        asm volatile("s_waitcnt vmcnt(0)" ::: "memory");
        __syncthreads();
#pragma unroll
        for (int ks = 0; ks < 2; ks++) {
            bf16x8 af[4], bfr[4];
#pragma unroll
            for (int i = 0; i < 4; i++) {
                int rA = (wm << 6) + (i << 4) + (l & 15);
                int rB = (wn << 6) + (i << 4) + (l & 15);
                af[i]  = *(const bf16x8*)(As + rA * 128 + (ks << 6) + k0b);
                bfr[i] = *(const bf16x8*)(Bs + rB * 128 + (ks << 6) + k0b);
            }
#pragma unroll
            for (int mi = 0; mi < 4; mi++)
#pragma unroll
                for (int ni = 0; ni < 4; ni++)
                    acc[mi][ni] = __builtin_amdgcn_mfma_f32_16x16x32_bf16(
                        af[mi], bfr[ni], acc[mi][ni], 0, 0, 0);
        }
        __syncthreads();
    }

    // epilogue: C/D map col=lane&15, row=(lane>>4)*4+j
    float taur[4][4];
#pragma unroll
    for (int mi = 0; mi < 4; mi++)
#pragma unroll
        for (int j = 0; j < 4; j++)
            taur[mi][j] = tau[m0 + (wm << 6) + (mi << 4) + ((l >> 4) << 2) + j];
#pragma unroll
    for (int ni = 0; ni < 4; ni++) {
        int f = f0 + n0l + (wn << 6) + (ni << 4) + (l & 15);
        float lbv = lbias[f];
#pragma unroll
        for (int mi = 0; mi < 4; mi++) {
            f32x4 v4 = acc[mi][ni];
#pragma unroll
            for (int j = 0; j < 4; j++) {
                float v = v4[j] + lbv;
                if (v >= taur[mi][j]) {
                    int r = m0 + (wm << 6) + (mi << 4) + ((l >> 4) << 2) + j;
                    unsigned pos = atomicAdd(&ccnt[r], 1u);
                    if (pos < CAP)
                        cand[(size_t)r * CAP + pos] =
                            ((unsigned)sortkey(f2bf(v)) << 16) | (unsigned)(32767 - f);
                }
            }
        }
    }
}

// ---------------- per-row: sort survivors, keep top-64 by key; flag pathological rows ----------------
__global__ __launch_bounds__(256) void select2_k(const unsigned* __restrict__ cand,
                                                 const unsigned* __restrict__ ccnt,
                                                 unsigned* __restrict__ flagv,
                                                 int* __restrict__ ridx,
                                                 int* __restrict__ runcnt) {
    int b = blockIdx.x, t = threadIdx.x;
    unsigned cnt = ccnt[b];
    int bad = (cnt < 48u || cnt > (unsigned)CAP);
    if (t == 0) { flagv[b] = bad; if (bad) runcnt[b] = 0; }
    if (bad) return;
    __shared__ unsigned srt[CAP];
    for (int i = t; i < CAP; i += 256)
        srt[i] = (i < (int)cnt) ? cand[(size_t)b * CAP + i] : 0u;
    __syncthreads();
    for (int k = 2; k <= CAP; k <<= 1) {
        for (int j = k >> 1; j > 0; j >>= 1) {
#pragma unroll
            for (int q = 0; q < CAP / 256; q++) {
                int i = t + q * 256;
                int ixj = i ^ j;
                if (ixj > i) {
                    unsigned a = srt[i], c2 = srt[ixj];
                    bool sw = ((i & k) == 0) ? (a < c2) : (a > c2);
                    if (sw) { srt[i] = c2; srt[ixj] = a; }
                }
            }
            __syncthreads();
        }
    }
    int nc = (int)cnt < RUNC ? (int)cnt : RUNC;
    if (t < nc) ridx[(size_t)b * RUNC + t] = 32767 - (int)(srt[t] & 0xFFFFu);
    if (t == 0) runcnt[b] = nc;
}

// ---------------- exact fallback for flagged rows (expected: zero rows) ----------------
__global__ __launch_bounds__(256) void fb_k(const unsigned* __restrict__ flagv,
                                            const float* __restrict__ x,
                                            const float* __restrict__ pb,
                                            const ushort* __restrict__ Wt16,
                                            const float* __restrict__ lb,
                                            int* __restrict__ ridx,
                                            int* __restrict__ runcnt) {
    int b = blockIdx.x;
    if (!flagv[b]) return;
    int t = threadIdx.x;
    __shared__ float xs[DD];
    __shared__ unsigned hist[256];
    __shared__ int s_cb, s_cum, s_T, s_pos;
    for (int i = t; i < DD; i += 256) xs[i] = x[(size_t)b * DD + i] - pb[i];
    hist[t] = 0;
    if (t == 0) s_pos = 0;
    __syncthreads();
    for (int f = t; f < FF; f += 256) {
        const ushort* wr = Wt16 + (size_t)f * DD;
        float s = 0.f;
        for (int d = 0; d < DD; d++) s += xs[d] * bf2f(wr[d]);
        ushort k = sortkey(f2bf(s + lb[f]));
        atomicAdd(&hist[k >> 8], 1u);
    }
    __syncthreads();
    if (t == 0) {
        int cum = 0, cb2 = 0;
        for (int i = 255; i >= 0; i--) {
            if (cum + (int)hist[i] >= 48) { cb2 = i; break; }
            cum += (int)hist[i];
        }
        s_cb = cb2; s_cum = cum;
    }
    __syncthreads();
    int cb2 = s_cb;
    hist[t] = 0;
    __syncthreads();
    for (int f = t; f < FF; f += 256) {
        const ushort* wr = Wt16 + (size_t)f * DD;
        float s = 0.f;
        for (int d = 0; d < DD; d++) s += xs[d] * bf2f(wr[d]);
        ushort k = sortkey(f2bf(s + lb[f]));
        if ((int)(k >> 8) == cb2) atomicAdd(&hist[k & 0xFF], 1u);
    }
    __syncthreads();
    if (t == 0) {
        int cum = s_cum, T = cb2 << 8;
        for (int fb2 = 255; fb2 >= 0; fb2--) {
            if (cum + (int)hist[fb2] >= 48) { T = (cb2 << 8) | fb2; break; }
            cum += (int)hist[fb2];
        }
        s_T = T;
    }
    __syncthreads();
    unsigned T = (unsigned)s_T;
    for (int f = t; f < FF; f += 256) {
        const ushort* wr = Wt16 + (size_t)f * DD;
        float s = 0.f;
        for (int d = 0; d < DD; d++) s += xs[d] * bf2f(wr[d]);
        ushort k = sortkey(f2bf(s + lb[f]));
        if (k >= T) {
            int p = atomicAdd(&s_pos, 1);
            if (p < RUNC) ridx[(size_t)b * RUNC + p] = f;
        }
    }
    __syncthreads();
    if (t == 0) runcnt[b] = s_pos < RUNC ? s_pos : RUNC;
}

// ---------------- refine: fp64 re-dot of candidates, exact top-32 ----------------
__global__ __launch_bounds__(256) void refine_k(const float* __restrict__ x,
                                                const float* __restrict__ pb,
                                                const float* __restrict__ We,
                                                const float* __restrict__ Wt32,
                                                const float* __restrict__ lb,
                                                const int* __restrict__ runidx,
                                                const int* __restrict__ runcnt,
                                                int use_t,
                                                int* __restrict__ sidx,
                                                float* __restrict__ sval) {
    int b = blockIdx.x, t = threadIdx.x, l = t & 63, w = t >> 6;
    __shared__ float xs[DD];
    __shared__ int ci[RUNC];
    __shared__ float cv[RUNC];
    for (int i = t; i < DD; i += 256) xs[i] = x[(size_t)b * DD + i] - pb[i];
    int c = runcnt[b]; if (c > RUNC) c = RUNC;
    if (t < RUNC) cv[t] = -1e30f;
    if (t < c) ci[t] = runidx[(size_t)b * RUNC + t];
    __syncthreads();
    for (int j = w; j < c; j += 4) {
        int f = ci[j];
        double s = 0.0;
        if (use_t) {
            const float* wr = Wt32 + (size_t)f * DD;
#pragma unroll
            for (int q = 0; q < 12; q++)
                s = fma((double)wr[l + 64 * q], (double)xs[l + 64 * q], s);
        } else {
#pragma unroll
            for (int q = 0; q < 12; q++)
                s = fma((double)We[(size_t)(l + 64 * q) * FF + f], (double)xs[l + 64 * q], s);
        }
#pragma unroll
        for (int o = 32; o >= 1; o >>= 1) s += __shfl_down(s, o);
        if (l == 0) cv[j] = (float)(s + (double)lb[f]);
    }
    __syncthreads();
    if (w == 0) {
        float v0 = cv[l];
        int i0 = (l < c) ? ci[l] : 0x7FFFFFFF;
        for (int sel = 0; sel < TK; sel++) {
            float bv = v0; int bi = i0;
#pragma unroll
            for (int o = 32; o >= 1; o >>= 1) {
                float ov = __shfl_xor(bv, o);
                int oi = __shfl_xor(bi, o);
                if (ov > bv || (ov == bv && oi < bi)) { bv = ov; bi = oi; }
            }
            if (i0 == bi) v0 = -1e30f;
            if (l == 0) {
                sidx[(size_t)b * TK + sel] = bi;
                sval[(size_t)b * TK + sel] = bv > 0.f ? bv : 0.f;
            }
        }
    }
}

// ---------------- decode ----------------
__global__ __launch_bounds__(192) void decode_k(const float* __restrict__ sval,
                                                const int* __restrict__ sidx,
                                                const float* __restrict__ Wd,
                                                const float* __restrict__ pb,
                                                float* __restrict__ out) {
    int b = blockIdx.x, t = threadIdx.x;
    __shared__ float sv[TK];
    __shared__ int si[TK];
    if (t < TK) { sv[t] = sval[(size_t)b * TK + t]; si[t] = sidx[(size_t)b * TK + t]; }
    __syncthreads();
    float4 acc = ((const float4*)pb)[t];
#pragma unroll 4
    for (int j = 0; j < TK; j++) {
        float v = sv[j];
        float4 wv = ((const float4*)(Wd + (size_t)si[j] * DD))[t];
        acc.x += v * wv.x; acc.y += v * wv.y;
        acc.z += v * wv.z; acc.w += v * wv.w;
    }
    ((float4*)out)[(size_t)b * (DD / 4) + t] = acc;
}

extern "C" void kernel_launch(void* const* d_in, const int* in_sizes, int n_in,
                              void* d_out, int out_size, void* d_ws, size_t ws_size,
                              hipStream_t stream) {
    const float* x  = (const float*)d_in[0];
    const float* pb = (const float*)d_in[1];
    const float* We = (const float*)d_in[2];
    const float* lb = (const float*)d_in[3];
    const float* Wd = (const float*)d_in[4];
    float* out = (float*)d_out;
    char* ws = (char*)d_ws;
    (void)in_sizes; (void)n_in; (void)out_size;

    const size_t SZ_X16  = (size_t)NB * DD * 2;        // 12.6 MB
    const size_t SZ_WT16 = (size_t)FF * DD * 2;        // 50.3 MB
    const size_t SZ_WT32 = (size_t)FF * DD * 4;        // 100.7 MB
    const size_t SZ_CAND = (size_t)NB * CAP * 4;       // 33.6 MB
    const size_t SZ_CTRL = (size_t)NB * 4 * 2 + NS2 * 4;
    const size_t SZ_TAU  = (size_t)NB * 4;
    const size_t SZ_RIDX = (size_t)NB * RUNC * 4;
    const size_t SZ_RCNT = (size_t)NB * 4;
    const size_t SZ_SIDX = (size_t)NB * TK * 4;
    const size_t SZ_SVAL = (size_t)NB * TK * 4;

    size_t need_base = SZ_X16 + SZ_WT16 + SZ_CAND + SZ_CTRL + SZ_TAU +
                       SZ_RIDX + SZ_RCNT + SZ_SIDX + SZ_SVAL;
    int use_t = (ws_size >= need_base + SZ_WT32) ? 1 : 0;

    size_t off = 0;
    ushort* x16   = (ushort*)(ws + off); off += SZ_X16;
    ushort* Wt16  = (ushort*)(ws + off); off += SZ_WT16;
    float*  Wt32  = nullptr;
    if (use_t) { Wt32 = (float*)(ws + off); off += SZ_WT32; }
    unsigned* ccnt = (unsigned*)(ws + off);            // start of memset region
    char* ctrl0   = (char*)(ws + off); off += (size_t)NB * 4;
    unsigned* flagv = (unsigned*)(ws + off); off += (size_t)NB * 4;
    float* s2part = (float*)(ws + off); off += NS2 * 4;
    size_t ctrl_bytes = (size_t)((ws + off) - ctrl0);
    float* tau    = (float*)(ws + off); off += SZ_TAU;
    unsigned* cand = (unsigned*)(ws + off); off += SZ_CAND;
    int* ridx     = (int*)(ws + off); off += SZ_RIDX;
    int* rcnt     = (int*)(ws + off); off += SZ_RCNT;
    int* sidx     = (int*)(ws + off); off += SZ_SIDX;
    float* sval   = (float*)(ws + off); off += SZ_SVAL;

    hipMemsetAsync(ctrl0, 0, ctrl_bytes, stream);
    prep_x_k<<<2048, 256, 0, stream>>>(x, pb, x16);
    prep_w_k<<<dim3(FF / 32, DD / 32), 256, 0, stream>>>(We, Wt16, Wt32, s2part);
    rn_k<<<NB / 4, 256, 0, stream>>>(x, pb, s2part, tau);
    for (int c = 0; c < FF / FC; ++c)
        gemm_k<<<(NB / 128) * (FC / 128), 256, 0, stream>>>(
            x16, Wt16, lb, tau, cand, ccnt, c * FC, FC);
    select2_k<<<NB, 256, 0, stream>>>(cand, ccnt, flagv, ridx, rcnt);
    fb_k<<<NB, 256, 0, stream>>>(flagv, x, pb, Wt16, lb, ridx, rcnt);
    refine_k<<<NB, 256, 0, stream>>>(x, pb, We, Wt32, lb, ridx, rcnt, use_t, sidx, sval);
    decode_k<<<NB, 192, 0, stream>>>(sval, sidx, Wd, pb, out);
}

// Round 7
// 1437.412 us; speedup vs baseline: 1.8161x; 1.8161x over previous
//
#include <hip/hip_runtime.h>
#include <stdint.h>

#define GAS __attribute__((address_space(1)))
#define LAS __attribute__((address_space(3)))

typedef __attribute__((ext_vector_type(8))) short bf16x8;
typedef __attribute__((ext_vector_type(4))) float f32x4;

static constexpr int NB = 8192;    // batch
static constexpr int DD = 768;     // model dim (K)
static constexpr int FF = 32768;   // latent dim (N)
static constexpr int TK = 32;      // top-k
static constexpr int RUNC = 64;    // refined candidate cap per row
static constexpr int SLOT = 8;     // survivor slots per (row, 128-col segment)
static constexpr int NSEG = FF / 128;  // 256 segments per row
static constexpr int SORTN = 1024; // select2 sort size
static constexpr int NS2 = 256;    // partial-sum slots for mean(W^2)
static constexpr int FC = 8192;    // F-chunk

__device__ __forceinline__ ushort f2bf(float f) {
    unsigned x = __float_as_uint(f);
    unsigned r = (x + 0x7FFFu + ((x >> 16) & 1u)) >> 16;
    return (ushort)r;
}
__device__ __forceinline__ ushort sortkey(ushort u) {
    return (u & 0x8000u) ? (ushort)(u ^ 0xFFFFu) : (ushort)(u | 0x8000u);
}
__device__ __forceinline__ float bf2f(ushort u) {
    return __uint_as_float(((unsigned)u) << 16);
}
__device__ __forceinline__ void gload_lds16(const void* g, void* l) {
    __builtin_amdgcn_global_load_lds((const GAS unsigned int*)g,
                                     (LAS unsigned int*)l, 16, 0, 0);
}

// ---------------- prep: x_bf16 = bf16(x - pre_bias) ----------------
__global__ __launch_bounds__(256) void prep_x_k(const float* __restrict__ x,
                                                const float* __restrict__ pb,
                                                ushort* __restrict__ x16) {
    const int n4 = NB * DD / 4;
    for (int i = blockIdx.x * 256 + threadIdx.x; i < n4; i += gridDim.x * 256) {
        float4 v = ((const float4*)x)[i];
        float4 p = ((const float4*)pb)[i % (DD / 4)];
        ushort4 o;
        o.x = f2bf(v.x - p.x); o.y = f2bf(v.y - p.y);
        o.z = f2bf(v.z - p.z); o.w = f2bf(v.w - p.w);
        ((ushort4*)x16)[i] = o;
    }
}

// ------------- prep: transpose W_enc [D,F] -> Wt [F,D] (bf16 + f32) + sum(W^2) -------------
__global__ __launch_bounds__(256) void prep_w_k(const float* __restrict__ W,
                                                ushort* __restrict__ Wt16,
                                                float* __restrict__ Wt32,
                                                float* __restrict__ s2part) {
    __shared__ float tile[32][33];
    int f0 = blockIdx.x * 32, d0 = blockIdx.y * 32;
    int tx = threadIdx.x & 31, ty = threadIdx.x >> 5;  // ty 0..7
    float ss = 0.f;
#pragma unroll
    for (int q = 0; q < 4; q++) {
        int dl = ty + q * 8;
        float v = W[(size_t)(d0 + dl) * FF + f0 + tx];
        tile[dl][tx] = v;
        ss += v * v;
    }
#pragma unroll
    for (int o = 32; o >= 1; o >>= 1) ss += __shfl_down(ss, o);
    if ((threadIdx.x & 63) == 0) {
        int slot = (blockIdx.x * 97 + blockIdx.y * 13 + (threadIdx.x >> 6)) & (NS2 - 1);
        atomicAdd(&s2part[slot], ss);
    }
    __syncthreads();
#pragma unroll
    for (int q = 0; q < 4; q++) {
        int fl = ty + q * 8;
        float v = tile[tx][fl];
        size_t o = (size_t)(f0 + fl) * DD + d0 + tx;
        Wt16[o] = f2bf(v);
        if (Wt32) Wt32[o] = v;
    }
}

// ---------------- per-row threshold: tau[b] = 2.5 * sqrt(mean(W^2)) * ||x_b - pb|| ----------------
__global__ __launch_bounds__(256) void rn_k(const float* __restrict__ x,
                                            const float* __restrict__ pb,
                                            const float* __restrict__ s2part,
                                            float* __restrict__ tau) {
    int t = threadIdx.x, l = t & 63, w = t >> 6;
    __shared__ float wsum[4];
    __shared__ float s2m;
    float p = s2part[t];  // NS2 == 256
#pragma unroll
    for (int o = 32; o >= 1; o >>= 1) p += __shfl_down(p, o);
    if (l == 0) wsum[w] = p;
    __syncthreads();
    if (t == 0) s2m = (wsum[0] + wsum[1] + wsum[2] + wsum[3]) / ((float)DD * (float)FF);
    __syncthreads();
    int row = blockIdx.x * 4 + w;
    float ss = 0.f;
#pragma unroll
    for (int q = 0; q < 12; q++) {
        int d = l + 64 * q;
        float v = x[(size_t)row * DD + d] - pb[d];
        ss += v * v;
    }
#pragma unroll
    for (int o = 32; o >= 1; o >>= 1) ss += __shfl_down(ss, o);
    if (l == 0) tau[row] = 2.5f * sqrtf(s2m * ss);
}

// ---------------- bf16 MFMA GEMM + fused filter; LDS-buffered append, no global atomics-w-return ----
// 128x128 tile, BK=64, 4 waves (2x2), each wave 64x64 via 4x4 frags of 16x16x32.
__global__ __launch_bounds__(256) void gemm_k(const ushort* __restrict__ A,
                                              const ushort* __restrict__ Bt,
                                              const float* __restrict__ lbias,
                                              const float* __restrict__ tau,
                                              unsigned* __restrict__ cand,
                                              unsigned* __restrict__ rowbad,
                                              int f0, int Fcn) {
    __shared__ __align__(16) char smem[32768];
    char* As = smem;
    char* Bs = smem + 16384;

    int ntil = Fcn >> 7;                     // 64
    int nwg = (NB / 128) * ntil;             // 4096, %8==0
    int cpx = nwg >> 3;
    int bid = (int)blockIdx.x;
    int wg = (bid & 7) * cpx + (bid >> 3);   // bijective XCD swizzle
    int mt = wg / ntil, nt = wg % ntil;
    int m0 = mt << 7, n0l = nt << 7;

    int t = threadIdx.x, l = t & 63;
    int w = t >> 6, wm = w >> 1, wn = w & 1;

    int rs = t >> 3, cs = t & 7;
    const ushort* ga = A + (size_t)(m0 + rs) * DD + cs * 8;
    const ushort* gb = Bt + (size_t)(f0 + n0l + rs) * DD + cs * 8;
    char* lA = As + t * 16;
    char* lB = Bs + t * 16;

    f32x4 acc[4][4] = {};
    int k0b = (l >> 4) << 4;

    for (int kt = 0; kt < DD; kt += 64) {
#pragma unroll
        for (int i = 0; i < 4; i++) {
            gload_lds16(ga + kt + (size_t)(i * 32) * DD, lA + i * 4096);
            gload_lds16(gb + kt + (size_t)(i * 32) * DD, lB + i * 4096);
        }
        asm volatile("s_waitcnt vmcnt(0)" ::: "memory");
        __syncthreads();
#pragma unroll
        for (int ks = 0; ks < 2; ks++) {
            bf16x8 af[4], bfr[4];
#pragma unroll
            for (int i = 0; i < 4; i++) {
                int rA = (wm << 6) + (i << 4) + (l & 15);
                int rB = (wn << 6) + (i << 4) + (l & 15);
                af[i]  = *(const bf16x8*)(As + rA * 128 + (ks << 6) + k0b);
                bfr[i] = *(const bf16x8*)(Bs + rB * 128 + (ks << 6) + k0b);
            }
#pragma unroll
            for (int mi = 0; mi < 4; mi++)
#pragma unroll
                for (int ni = 0; ni < 4; ni++)
                    acc[mi][ni] = __builtin_amdgcn_mfma_f32_16x16x32_bf16(
                        af[mi], bfr[ni], acc[mi][ni], 0, 0, 0);
        }
        __syncthreads();
    }

    // ---- epilogue: C/D map col=lane&15, row=(lane>>4)*4+j; LDS-buffered survivor append ----
    int* lcnt = (int*)smem;                       // [128]
    unsigned* lbuf = (unsigned*)(smem + 512);     // [128][SLOT]
    for (int i = t; i < 128; i += 256) lcnt[i] = 0;
    __syncthreads();
    float taur[4][4];
#pragma unroll
    for (int mi = 0; mi < 4; mi++)
#pragma unroll
        for (int j = 0; j < 4; j++)
            taur[mi][j] = tau[m0 + (wm << 6) + (mi << 4) + ((l >> 4) << 2) + j];
#pragma unroll
    for (int ni = 0; ni < 4; ni++) {
        int f = f0 + n0l + (wn << 6) + (ni << 4) + (l & 15);
        float lbv = lbias[f];
#pragma unroll
        for (int mi = 0; mi < 4; mi++) {
            f32x4 v4 = acc[mi][ni];
#pragma unroll
            for (int j = 0; j < 4; j++) {
                float v = v4[j] + lbv;
                if (v >= taur[mi][j]) {
                    int lr = (wm << 6) + (mi << 4) + ((l >> 4) << 2) + j;  // local row
                    int p = atomicAdd(&lcnt[lr], 1);                       // LDS atomic
                    if (p < SLOT)
                        lbuf[lr * SLOT + p] =
                            ((unsigned)sortkey(f2bf(v)) << 16) | (unsigned)(32767 - f);
                }
            }
        }
    }
    __syncthreads();
    if (t < 128) {
        int c = lcnt[t];
        int gr = m0 + t;
        if (c > SLOT) { atomicOr(&rowbad[gr], 1u); c = SLOT; }  // fire-and-forget, ~never
        int gseg = (f0 >> 7) + nt;
        unsigned* dst = cand + (size_t)gr * (NSEG * SLOT) + gseg * SLOT;
        for (int s = 0; s < c; s++) dst[s] = lbuf[t * SLOT + s];
    }
}

// ---------------- per-row: gather nonzero slots, sort, keep top-64; flag pathological rows ----------------
__global__ __launch_bounds__(256) void select2_k(const unsigned* __restrict__ cand,
                                                 const unsigned* __restrict__ rowbad,
                                                 unsigned* __restrict__ flagv,
                                                 int* __restrict__ ridx,
                                                 int* __restrict__ runcnt) {
    int b = blockIdx.x, t = threadIdx.x;
    __shared__ unsigned srt[SORTN];
    __shared__ int s_cnt;
    for (int i = t; i < SORTN; i += 256) srt[i] = 0;
    if (t == 0) s_cnt = 0;
    __syncthreads();
    const uint4* src = (const uint4*)(cand + (size_t)b * (NSEG * SLOT));
    for (int i = t; i < NSEG * SLOT / 4; i += 256) {
        uint4 v4 = src[i];
        unsigned d[4] = {v4.x, v4.y, v4.z, v4.w};
#pragma unroll
        for (int q = 0; q < 4; q++)
            if (d[q]) {
                int p = atomicAdd(&s_cnt, 1);
                if (p < SORTN) srt[p] = d[q];
            }
    }
    __syncthreads();
    int cnt = s_cnt;
    int bad = (rowbad[b] != 0u) || cnt < 48 || cnt > SORTN;
    if (t == 0) { flagv[b] = bad; if (bad) runcnt[b] = 0; }
    if (bad) return;
    for (int k = 2; k <= SORTN; k <<= 1) {
        for (int j = k >> 1; j > 0; j >>= 1) {
#pragma unroll
            for (int q = 0; q < SORTN / 256; q++) {
                int i = t + q * 256;
                int ixj = i ^ j;
                if (ixj > i) {
                    unsigned a = srt[i], c2 = srt[ixj];
                    bool sw = ((i & k) == 0) ? (a < c2) : (a > c2);
                    if (sw) { srt[i] = c2; srt[ixj] = a; }
                }
            }
            __syncthreads();
        }
    }
    int nc = cnt < RUNC ? cnt : RUNC;
    if (t < nc) ridx[(size_t)b * RUNC + t] = 32767 - (int)(srt[t] & 0xFFFFu);
    if (t == 0) runcnt[b] = nc;
}

// ---------------- exact fallback for flagged rows (expected: zero rows) ----------------
__global__ __launch_bounds__(256) void fb_k(const unsigned* __restrict__ flagv,
                                            const float* __restrict__ x,
                                            const float* __restrict__ pb,
                                            const ushort* __restrict__ Wt16,
                                            const float* __restrict__ lb,
                                            int* __restrict__ ridx,
                                            int* __restrict__ runcnt) {
    int b = blockIdx.x;
    if (!flagv[b]) return;
    int t = threadIdx.x;
    __shared__ float xs[DD];
    __shared__ unsigned hist[256];
    __shared__ int s_cb, s_cum, s_T, s_pos;
    for (int i = t; i < DD; i += 256) xs[i] = x[(size_t)b * DD + i] - pb[i];
    hist[t] = 0;
    if (t == 0) s_pos = 0;
    __syncthreads();
    for (int f = t; f < FF; f += 256) {
        const ushort* wr = Wt16 + (size_t)f * DD;
        float s = 0.f;
        for (int d = 0; d < DD; d++) s += xs[d] * bf2f(wr[d]);
        ushort k = sortkey(f2bf(s + lb[f]));
        atomicAdd(&hist[k >> 8], 1u);
    }
    __syncthreads();
    if (t == 0) {
        int cum = 0, cb2 = 0;
        for (int i = 255; i >= 0; i--) {
            if (cum + (int)hist[i] >= 48) { cb2 = i; break; }
            cum += (int)hist[i];
        }
        s_cb = cb2; s_cum = cum;
    }
    __syncthreads();
    int cb2 = s_cb;
    hist[t] = 0;
    __syncthreads();
    for (int f = t; f < FF; f += 256) {
        const ushort* wr = Wt16 + (size_t)f * DD;
        float s = 0.f;
        for (int d = 0; d < DD; d++) s += xs[d] * bf2f(wr[d]);
        ushort k = sortkey(f2bf(s + lb[f]));
        if ((int)(k >> 8) == cb2) atomicAdd(&hist[k & 0xFF], 1u);
    }
    __syncthreads();
    if (t == 0) {
        int cum = s_cum, T = cb2 << 8;
        for (int fb2 = 255; fb2 >= 0; fb2--) {
            if (cum + (int)hist[fb2] >= 48) { T = (cb2 << 8) | fb2; break; }
            cum += (int)hist[fb2];
        }
        s_T = T;
    }
    __syncthreads();
    unsigned T = (unsigned)s_T;
    for (int f = t; f < FF; f += 256) {
        const ushort* wr = Wt16 + (size_t)f * DD;
        float s = 0.f;
        for (int d = 0; d < DD; d++) s += xs[d] * bf2f(wr[d]);
        ushort k = sortkey(f2bf(s + lb[f]));
        if (k >= T) {
            int p = atomicAdd(&s_pos, 1);
            if (p < RUNC) ridx[(size_t)b * RUNC + p] = f;
        }
    }
    __syncthreads();
    if (t == 0) runcnt[b] = s_pos < RUNC ? s_pos : RUNC;
}

// ---------------- refine: fp64 re-dot of candidates, exact top-32 ----------------
__global__ __launch_bounds__(256) void refine_k(const float* __restrict__ x,
                                                const float* __restrict__ pb,
                                                const float* __restrict__ We,
                                                const float* __restrict__ Wt32,
                                                const float* __restrict__ lb,
                                                const int* __restrict__ runidx,
                                                const int* __restrict__ runcnt,
                                                int use_t,
                                                int* __restrict__ sidx,
                                                float* __restrict__ sval) {
    int b = blockIdx.x, t = threadIdx.x, l = t & 63, w = t >> 6;
    __shared__ float xs[DD];
    __shared__ int ci[RUNC];
    __shared__ float cv[RUNC];
    for (int i = t; i < DD; i += 256) xs[i] = x[(size_t)b * DD + i] - pb[i];
    int c = runcnt[b]; if (c > RUNC) c = RUNC;
    if (t < RUNC) cv[t] = -1e30f;
    if (t < c) ci[t] = runidx[(size_t)b * RUNC + t];
    __syncthreads();
    for (int j = w; j < c; j += 4) {
        int f = ci[j];
        double s = 0.0;
        if (use_t) {
            const float* wr = Wt32 + (size_t)f * DD;
#pragma unroll
            for (int q = 0; q < 12; q++)
                s = fma((double)wr[l + 64 * q], (double)xs[l + 64 * q], s);
        } else {
#pragma unroll
            for (int q = 0; q < 12; q++)
                s = fma((double)We[(size_t)(l + 64 * q) * FF + f], (double)xs[l + 64 * q], s);
        }
#pragma unroll
        for (int o = 32; o >= 1; o >>= 1) s += __shfl_down(s, o);
        if (l == 0) cv[j] = (float)(s + (double)lb[f]);
    }
    __syncthreads();
    if (w == 0) {
        float v0 = cv[l];
        int i0 = (l < c) ? ci[l] : 0x7FFFFFFF;
        for (int sel = 0; sel < TK; sel++) {
            float bv = v0; int bi = i0;
#pragma unroll
            for (int o = 32; o >= 1; o >>= 1) {
                float ov = __shfl_xor(bv, o);
                int oi = __shfl_xor(bi, o);
                if (ov > bv || (ov == bv && oi < bi)) { bv = ov; bi = oi; }
            }
            if (i0 == bi) v0 = -1e30f;
            if (l == 0) {
                sidx[(size_t)b * TK + sel] = bi;
                sval[(size_t)b * TK + sel] = bv > 0.f ? bv : 0.f;
            }
        }
    }
}

// ---------------- decode ----------------
__global__ __launch_bounds__(192) void decode_k(const float* __restrict__ sval,
                                                const int* __restrict__ sidx,
                                                const float* __restrict__ Wd,
                                                const float* __restrict__ pb,
                                                float* __restrict__ out) {
    int b = blockIdx.x, t = threadIdx.x;
    __shared__ float sv[TK];
    __shared__ int si[TK];
    if (t < TK) { sv[t] = sval[(size_t)b * TK + t]; si[t] = sidx[(size_t)b * TK + t]; }
    __syncthreads();
    float4 acc = ((const float4*)pb)[t];
#pragma unroll 4
    for (int j = 0; j < TK; j++) {
        float v = sv[j];
        float4 wv = ((const float4*)(Wd + (size_t)si[j] * DD))[t];
        acc.x += v * wv.x; acc.y += v * wv.y;
        acc.z += v * wv.z; acc.w += v * wv.w;
    }
    ((float4*)out)[(size_t)b * (DD / 4) + t] = acc;
}

extern "C" void kernel_launch(void* const* d_in, const int* in_sizes, int n_in,
                              void* d_out, int out_size, void* d_ws, size_t ws_size,
                              hipStream_t stream) {
    const float* x  = (const float*)d_in[0];
    const float* pb = (const float*)d_in[1];
    const float* We = (const float*)d_in[2];
    const float* lb = (const float*)d_in[3];
    const float* Wd = (const float*)d_in[4];
    float* out = (float*)d_out;
    char* ws = (char*)d_ws;
    (void)in_sizes; (void)n_in; (void)out_size;

    const size_t SZ_X16  = (size_t)NB * DD * 2;              // 12.6 MB
    const size_t SZ_WT16 = (size_t)FF * DD * 2;              // 50.3 MB
    const size_t SZ_WT32 = (size_t)FF * DD * 4;              // 100.7 MB
    const size_t SZ_CAND = (size_t)NB * NSEG * SLOT * 4;     // 67.1 MB
    const size_t SZ_TAU  = (size_t)NB * 4;
    const size_t SZ_RIDX = (size_t)NB * RUNC * 4;
    const size_t SZ_RCNT = (size_t)NB * 4;
    const size_t SZ_SIDX = (size_t)NB * TK * 4;
    const size_t SZ_SVAL = (size_t)NB * TK * 4;
    const size_t SZ_CTRL = (size_t)NB * 4 + NS2 * 4 + SZ_CAND;  // rowbad + s2part + cand

    size_t need_base = SZ_X16 + SZ_WT16 + SZ_CTRL + (size_t)NB * 4 /*flagv*/ +
                       SZ_TAU + SZ_RIDX + SZ_RCNT + SZ_SIDX + SZ_SVAL;
    int use_t = (ws_size >= need_base + SZ_WT32) ? 1 : 0;

    size_t off = 0;
    ushort* x16   = (ushort*)(ws + off); off += SZ_X16;
    ushort* Wt16  = (ushort*)(ws + off); off += SZ_WT16;
    float*  Wt32  = nullptr;
    if (use_t) { Wt32 = (float*)(ws + off); off += SZ_WT32; }
    char* ctrl0   = (char*)(ws + off);                       // memset region start
    unsigned* rowbad = (unsigned*)(ws + off); off += (size_t)NB * 4;
    float* s2part = (float*)(ws + off); off += NS2 * 4;
    unsigned* cand = (unsigned*)(ws + off); off += SZ_CAND;
    size_t ctrl_bytes = (size_t)((ws + off) - ctrl0);
    unsigned* flagv = (unsigned*)(ws + off); off += (size_t)NB * 4;
    float* tau    = (float*)(ws + off); off += SZ_TAU;
    int* ridx     = (int*)(ws + off); off += SZ_RIDX;
    int* rcnt     = (int*)(ws + off); off += SZ_RCNT;
    int* sidx     = (int*)(ws + off); off += SZ_SIDX;
    float* sval   = (float*)(ws + off); off += SZ_SVAL;

    hipMemsetAsync(ctrl0, 0, ctrl_bytes, stream);
    prep_x_k<<<2048, 256, 0, stream>>>(x, pb, x16);
    prep_w_k<<<dim3(FF / 32, DD / 32), 256, 0, stream>>>(We, Wt16, Wt32, s2part);
    rn_k<<<NB / 4, 256, 0, stream>>>(x, pb, s2part, tau);
    for (int c = 0; c < FF / FC; ++c)
        gemm_k<<<(NB / 128) * (FC / 128), 256, 0, stream>>>(
            x16, Wt16, lb, tau, cand, rowbad, c * FC, FC);
    select2_k<<<NB, 256, 0, stream>>>(cand, rowbad, flagv, ridx, rcnt);
    fb_k<<<NB, 256, 0, stream>>>(flagv, x, pb, Wt16, lb, ridx, rcnt);
    refine_k<<<NB, 256, 0, stream>>>(x, pb, We, Wt32, lb, ridx, rcnt, use_t, sidx, sval);
    decode_k<<<NB, 192, 0, stream>>>(sval, sidx, Wd, pb, out);
}

// Round 9
// 1111.020 us; speedup vs baseline: 2.3496x; 1.2938x over previous
//
#include <hip/hip_runtime.h>
#include <stdint.h>

#define GAS __attribute__((address_space(1)))
#define LAS __attribute__((address_space(3)))

typedef __attribute__((ext_vector_type(8))) short bf16x8;
typedef __attribute__((ext_vector_type(4))) float f32x4;

static constexpr int NB = 8192;    // batch
static constexpr int DD = 768;     // model dim (K)
static constexpr int FF = 32768;   // latent dim (N)
static constexpr int TK = 32;      // top-k
static constexpr int RUNC = 48;    // refined candidate cap per row
static constexpr int SLOT = 8;     // survivor slots per (row, 128-col segment)
static constexpr int NSEG = FF / 128;  // 256 segments per row
static constexpr int SORTN = 1024; // select2 sort size
static constexpr int NS2 = 256;    // partial-sum slots for mean(W^2)
static constexpr int NKT = DD / 32;    // 24 K-tiles of 32
static constexpr int PQ = 256 * 32;    // panel elements per K-tile (8192)

__device__ __forceinline__ ushort f2bf(float f) {
    unsigned x = __float_as_uint(f);
    unsigned r = (x + 0x7FFFu + ((x >> 16) & 1u)) >> 16;
    return (ushort)r;
}
__device__ __forceinline__ ushort sortkey(ushort u) {
    return (u & 0x8000u) ? (ushort)(u ^ 0xFFFFu) : (ushort)(u | 0x8000u);
}
__device__ __forceinline__ float bf2f(ushort u) {
    return __uint_as_float(((unsigned)u) << 16);
}
__device__ __forceinline__ void gload_lds16(const void* g, void* l) {
    __builtin_amdgcn_global_load_lds((const GAS unsigned int*)g,
                                     (LAS unsigned int*)l, 16, 0, 0);
}
// panel element offset: [vtile=v>>8][kt=d>>5][v&255][d&31]
__device__ __forceinline__ size_t pan_off(int v, int d) {
    return ((size_t)(v >> 8) * NKT + (d >> 5)) * PQ + ((v & 255) << 5) + (d & 31);
}

// ---------------- prep: A panels = bf16(x - pre_bias), plain-packed ----------------
__global__ __launch_bounds__(256) void prep_x_k(const float* __restrict__ x,
                                                const float* __restrict__ pb,
                                                ushort* __restrict__ Ap) {
    const int n4 = NB * DD / 4;
    for (int i = blockIdx.x * 256 + threadIdx.x; i < n4; i += gridDim.x * 256) {
        int b = i / (DD / 4), dq = (i % (DD / 4)) * 4;
        float4 v = ((const float4*)x)[i];
        float4 p = ((const float4*)pb)[i % (DD / 4)];
        ushort4 o;
        o.x = f2bf(v.x - p.x); o.y = f2bf(v.y - p.y);
        o.z = f2bf(v.z - p.z); o.w = f2bf(v.w - p.w);
        *(ushort4*)(Ap + pan_off(b, dq)) = o;
    }
}

// ------------- prep: W_enc [D,F] -> B panels (bf16, plain-packed) + Wt32 [F,D] + sum(W^2) -------------
__global__ __launch_bounds__(256) void prep_w_k(const float* __restrict__ W,
                                                ushort* __restrict__ Bp,
                                                float* __restrict__ Wt32,
                                                float* __restrict__ s2part) {
    __shared__ float tile[32][33];
    int f0 = blockIdx.x * 32, d0 = blockIdx.y * 32;
    int tx = threadIdx.x & 31, ty = threadIdx.x >> 5;  // ty 0..7
    float ss = 0.f;
#pragma unroll
    for (int q = 0; q < 4; q++) {
        int dl = ty + q * 8;
        float v = W[(size_t)(d0 + dl) * FF + f0 + tx];
        tile[dl][tx] = v;
        ss += v * v;
    }
#pragma unroll
    for (int o = 32; o >= 1; o >>= 1) ss += __shfl_down(ss, o);
    if ((threadIdx.x & 63) == 0) {
        int slot = (blockIdx.x * 97 + blockIdx.y * 13 + (threadIdx.x >> 6)) & (NS2 - 1);
        atomicAdd(&s2part[slot], ss);
    }
    __syncthreads();
#pragma unroll
    for (int q = 0; q < 4; q++) {
        int fl = ty + q * 8;
        float v = tile[tx][fl];
        int f = f0 + fl, d = d0 + tx;
        Bp[pan_off(f, d)] = f2bf(v);
        if (Wt32) Wt32[(size_t)f * DD + d] = v;
    }
}

// ---------------- per-row threshold: tau[b] = 2.5 * sqrt(mean(W^2)) * ||x_b - pb|| ----------------
__global__ __launch_bounds__(256) void rn_k(const float* __restrict__ x,
                                            const float* __restrict__ pb,
                                            const float* __restrict__ s2part,
                                            float* __restrict__ tau) {
    int t = threadIdx.x, l = t & 63, w = t >> 6;
    __shared__ float wsum[4];
    __shared__ float s2m;
    float p = s2part[t];  // NS2 == 256
#pragma unroll
    for (int o = 32; o >= 1; o >>= 1) p += __shfl_down(p, o);
    if (l == 0) wsum[w] = p;
    __syncthreads();
    if (t == 0) s2m = (wsum[0] + wsum[1] + wsum[2] + wsum[3]) / ((float)DD * (float)FF);
    __syncthreads();
    int row = blockIdx.x * 4 + w;
    float ss = 0.f;
#pragma unroll
    for (int q = 0; q < 12; q++) {
        int d = l + 64 * q;
        float v = x[(size_t)row * DD + d] - pb[d];
        ss += v * v;
    }
#pragma unroll
    for (int o = 32; o >= 1; o >>= 1) ss += __shfl_down(ss, o);
    if (l == 0) tau[row] = 2.5f * sqrtf(s2m * ss);
}

// ---------------- 256x256 bf16 MFMA GEMM, ring-3 K-tile pipeline (BK=32), counted vmcnt ----------------
// 8 waves (2M x 4N), per-wave 128x64 out = acc[8][4] of 16x16x32 frags.
// T2 swizzle: linear gload_lds dest; source pre-permuted slot^(row&3); read slot^(r&3).
// Fused filter epilogue (LDS-buffered append, r7-verified).
#define MFMA16(A0, A1, A2, A3, MB)                                            \
    _Pragma("unroll")                                                         \
    for (int ni = 0; ni < 4; ni++) {                                          \
        acc[MB + 0][ni] = __builtin_amdgcn_mfma_f32_16x16x32_bf16(A0, bfr[ni], acc[MB + 0][ni], 0, 0, 0); \
        acc[MB + 1][ni] = __builtin_amdgcn_mfma_f32_16x16x32_bf16(A1, bfr[ni], acc[MB + 1][ni], 0, 0, 0); \
        acc[MB + 2][ni] = __builtin_amdgcn_mfma_f32_16x16x32_bf16(A2, bfr[ni], acc[MB + 2][ni], 0, 0, 0); \
        acc[MB + 3][ni] = __builtin_amdgcn_mfma_f32_16x16x32_bf16(A3, bfr[ni], acc[MB + 3][ni], 0, 0, 0); \
    }

__global__ __launch_bounds__(512, 2) void gemm_k(const ushort* __restrict__ Ap,
                                                 const ushort* __restrict__ Bp,
                                                 const float* __restrict__ lbias,
                                                 const float* __restrict__ tau,
                                                 unsigned* __restrict__ cand,
                                                 unsigned* __restrict__ rowbad) {
    __shared__ __align__(16) char smem[98304];   // 3 ring slots x (A 16K + B 16K)

    int bid = (int)blockIdx.x;                   // nwg = 4096, %8==0
    int wg = (bid & 7) * 512 + (bid >> 3);       // bijective XCD swizzle, nt-major per XCD
    int mt = wg >> 7, nt = wg & 127;
    int m0 = mt << 8, n0 = nt << 8;

    int t = threadIdx.x, l = t & 63, w = t >> 6;
    int wm = w >> 2, wn = w & 3;                 // 2M x 4N

    // ---- staging maps: slot index s = q*512+t; s<1024 -> A, else B ----
    int soff[4], ldo[4];
#pragma unroll
    for (int q = 0; q < 4; q++) {
        int s = q * 512 + t;
        int rr = (s & 1023) >> 2;                // row 0..255
        int sl = (s & 3) ^ (rr & 3);             // inverse swizzle (involution)
        soff[q] = rr * 32 + sl * 8;              // elements within K-tile panel
        ldo[q] = s * 16;                         // linear LDS byte (A 0..32K-16)
    }
    const ushort* apan = Ap + (size_t)mt * NKT * PQ;
    const ushort* bpan = Bp + (size_t)nt * NKT * PQ;
    const ushort* sp0 = apan + soff[0];
    const ushort* sp1 = apan + soff[1];
    const ushort* sp2 = bpan + soff[2];
    const ushort* sp3 = bpan + soff[3];

    // ---- frag read bases (swizzled): byte = r*64 + ((l>>4 ^ r&3)<<4); r&3 == l&3 ----
    int xsl = ((l >> 4) ^ (l & 3)) << 4;
    int aro = (wm * 128 + (l & 15)) * 64 + xsl;
    int bro = (wn * 64 + (l & 15)) * 64 + xsl;

    f32x4 acc[8][4] = {};

    // ---- prologue: stage K-tiles 0,1 ----
    gload_lds16(sp0, smem + ldo[0]); gload_lds16(sp1, smem + ldo[1]);
    gload_lds16(sp2, smem + ldo[2]); gload_lds16(sp3, smem + ldo[3]);
    gload_lds16(sp0 + PQ, smem + 32768 + ldo[0]); gload_lds16(sp1 + PQ, smem + 32768 + ldo[1]);
    gload_lds16(sp2 + PQ, smem + 32768 + ldo[2]); gload_lds16(sp3 + PQ, smem + 32768 + ldo[3]);
    asm volatile("s_waitcnt vmcnt(0)" ::: "memory");
    __builtin_amdgcn_s_barrier();
    __builtin_amdgcn_sched_barrier(0);

    int cur = 0;
#pragma unroll 1
    for (int kt = 0; kt < NKT; kt++) {
        const char* Ar = smem + cur * 32768;
        const char* Br = Ar + 16384;
        int nxt = cur + 2; if (nxt >= 3) nxt -= 3;   // ring slot for kt+2 (freed at kt-1)
        char* dst = smem + nxt * 32768;
        const size_t ko = (size_t)(kt + 2) * PQ;
        bool st = kt < NKT - 2;

        // ---- phase 0: read af0-3 + bfr0-3, stage A-half of kt+2, MFMA mi 0-3 ----
        bf16x8 af0 = *(const bf16x8*)(Ar + aro);
        bf16x8 af1 = *(const bf16x8*)(Ar + aro + 1024);
        bf16x8 af2 = *(const bf16x8*)(Ar + aro + 2048);
        bf16x8 af3 = *(const bf16x8*)(Ar + aro + 3072);
        bf16x8 bfr[4];
        bfr[0] = *(const bf16x8*)(Br + bro);
        bfr[1] = *(const bf16x8*)(Br + bro + 1024);
        bfr[2] = *(const bf16x8*)(Br + bro + 2048);
        bfr[3] = *(const bf16x8*)(Br + bro + 3072);
        if (st) { gload_lds16(sp0 + ko, dst + ldo[0]); gload_lds16(sp1 + ko, dst + ldo[1]); }
        __builtin_amdgcn_s_barrier();
        __builtin_amdgcn_sched_barrier(0);
        __builtin_amdgcn_s_setprio(1);
        MFMA16(af0, af1, af2, af3, 0)
        __builtin_amdgcn_s_setprio(0);
        __builtin_amdgcn_s_barrier();
        __builtin_amdgcn_sched_barrier(0);

        // ---- phase 1: read af4-7, stage B-half of kt+2, counted vmcnt, MFMA mi 4-7 ----
        bf16x8 af4 = *(const bf16x8*)(Ar + aro + 4096);
        bf16x8 af5 = *(const bf16x8*)(Ar + aro + 5120);
        bf16x8 af6 = *(const bf16x8*)(Ar + aro + 6144);
        bf16x8 af7 = *(const bf16x8*)(Ar + aro + 7168);
        if (st) {
            gload_lds16(sp2 + ko, dst + ldo[2]); gload_lds16(sp3 + ko, dst + ldo[3]);
            asm volatile("s_waitcnt vmcnt(4)" ::: "memory");  // kt+1 fully landed; this iter's 4 may fly
        } else {
            asm volatile("s_waitcnt vmcnt(0)" ::: "memory");
        }
        __builtin_amdgcn_s_barrier();
        __builtin_amdgcn_sched_barrier(0);
        __builtin_amdgcn_s_setprio(1);
        MFMA16(af4, af5, af6, af7, 4)
        __builtin_amdgcn_s_setprio(0);
        __builtin_amdgcn_s_barrier();
        __builtin_amdgcn_sched_barrier(0);

        cur = cur + 1; if (cur == 3) cur = 0;
    }

    // ---- epilogue: reuse LDS; C/D map col=lane&15, row=(lane>>4)*4+j (r5-verified 8x4) ----
    int* lcnt = (int*)smem;                       // [256 rows][2 seg-halves]
    unsigned* lbuf = (unsigned*)(smem + 2048);    // [512][SLOT]
    __syncthreads();
    lcnt[t] = 0;
    __syncthreads();
    float lbv[4]; int fcol[4];
#pragma unroll
    for (int ni = 0; ni < 4; ni++) {
        fcol[ni] = n0 + wn * 64 + ni * 16 + (l & 15);
        lbv[ni] = lbias[fcol[ni]];
    }
    int sh = wn >> 1;                             // local 128-col segment half
#pragma unroll
    for (int mi = 0; mi < 8; mi++) {
        int rl = wm * 128 + mi * 16 + ((l >> 4) << 2);
        float4 tq = *(const float4*)(tau + m0 + rl);
        float tj[4] = {tq.x, tq.y, tq.z, tq.w};
#pragma unroll
        for (int ni = 0; ni < 4; ni++) {
            f32x4 v4 = acc[mi][ni];
#pragma unroll
            for (int j = 0; j < 4; j++) {
                float v = v4[j] + lbv[ni];
                if (v >= tj[j]) {
                    int idx = ((rl + j) << 1) + sh;
                    int p = atomicAdd(&lcnt[idx], 1);
                    if (p < SLOT)
                        lbuf[idx * SLOT + p] =
                            ((unsigned)sortkey(f2bf(v)) << 16) | (unsigned)(32767 - fcol[ni]);
                }
            }
        }
    }
    __syncthreads();
    {
        int row = t >> 1, sh2 = t & 1;
        int c = lcnt[t];
        int gr = m0 + row;
        if (c > SLOT) { atomicOr(&rowbad[gr], 1u); c = SLOT; }
        unsigned* dstc = cand + (size_t)gr * (NSEG * SLOT) + ((nt << 1) + sh2) * SLOT;
        for (int s2 = 0; s2 < c; s2++) dstc[s2] = lbuf[t * SLOT + s2];
    }
}

// ---------------- per-row: gather nonzero slots, sort, keep top-RUNC; flag pathological rows ----------------
__global__ __launch_bounds__(256) void select2_k(const unsigned* __restrict__ cand,
                                                 const unsigned* __restrict__ rowbad,
                                                 unsigned* __restrict__ flagv,
                                                 int* __restrict__ ridx,
                                                 int* __restrict__ runcnt) {
    int b = blockIdx.x, t = threadIdx.x;
    __shared__ unsigned srt[SORTN];
    __shared__ int s_cnt;
    for (int i = t; i < SORTN; i += 256) srt[i] = 0;
    if (t == 0) s_cnt = 0;
    __syncthreads();
    const uint4* src = (const uint4*)(cand + (size_t)b * (NSEG * SLOT));
    for (int i = t; i < NSEG * SLOT / 4; i += 256) {
        uint4 v4 = src[i];
        unsigned d[4] = {v4.x, v4.y, v4.z, v4.w};
#pragma unroll
        for (int q = 0; q < 4; q++)
            if (d[q]) {
                int p = atomicAdd(&s_cnt, 1);
                if (p < SORTN) srt[p] = d[q];
            }
    }
    __syncthreads();
    int cnt = s_cnt;
    int bad = (rowbad[b] != 0u) || cnt < 48 || cnt > SORTN;
    if (t == 0) { flagv[b] = bad; if (bad) runcnt[b] = 0; }
    if (bad) return;
    for (int k = 2; k <= SORTN; k <<= 1) {
        for (int j = k >> 1; j > 0; j >>= 1) {
#pragma unroll
            for (int q = 0; q < SORTN / 256; q++) {
                int i = t + q * 256;
                int ixj = i ^ j;
                if (ixj > i) {
                    unsigned a = srt[i], c2 = srt[ixj];
                    bool sw = ((i & k) == 0) ? (a < c2) : (a > c2);
                    if (sw) { srt[i] = c2; srt[ixj] = a; }
                }
            }
            __syncthreads();
        }
    }
    int nc = cnt < RUNC ? cnt : RUNC;
    if (t < nc) ridx[(size_t)b * RUNC + t] = 32767 - (int)(srt[t] & 0xFFFFu);
    if (t == 0) runcnt[b] = nc;
}

// ---------------- exact fallback for flagged rows (expected: zero rows) ----------------
__global__ __launch_bounds__(256) void fb_k(const unsigned* __restrict__ flagv,
                                            const float* __restrict__ x,
                                            const float* __restrict__ pb,
                                            const ushort* __restrict__ Bp,
                                            const float* __restrict__ lb,
                                            int* __restrict__ ridx,
                                            int* __restrict__ runcnt) {
    int b = blockIdx.x;
    if (!flagv[b]) return;
    int t = threadIdx.x;
    __shared__ float xs[DD];
    __shared__ unsigned hist[256];
    __shared__ int s_cb, s_cum, s_T, s_pos;
    for (int i = t; i < DD; i += 256) xs[i] = x[(size_t)b * DD + i] - pb[i];
    hist[t] = 0;
    if (t == 0) s_pos = 0;
    __syncthreads();
    for (int f = t; f < FF; f += 256) {
        float s = 0.f;
        for (int d = 0; d < DD; d++) s += xs[d] * bf2f(Bp[pan_off(f, d)]);
        ushort k = sortkey(f2bf(s + lb[f]));
        atomicAdd(&hist[k >> 8], 1u);
    }
    __syncthreads();
    if (t == 0) {
        int cum = 0, cb2 = 0;
        for (int i = 255; i >= 0; i--) {
            if (cum + (int)hist[i] >= 48) { cb2 = i; break; }
            cum += (int)hist[i];
        }
        s_cb = cb2; s_cum = cum;
    }
    __syncthreads();
    int cb2 = s_cb;
    hist[t] = 0;
    __syncthreads();
    for (int f = t; f < FF; f += 256) {
        float s = 0.f;
        for (int d = 0; d < DD; d++) s += xs[d] * bf2f(Bp[pan_off(f, d)]);
        ushort k = sortkey(f2bf(s + lb[f]));
        if ((int)(k >> 8) == cb2) atomicAdd(&hist[k & 0xFF], 1u);
    }
    __syncthreads();
    if (t == 0) {
        int cum = s_cum, T = cb2 << 8;
        for (int fb2 = 255; fb2 >= 0; fb2--) {
            if (cum + (int)hist[fb2] >= 48) { T = (cb2 << 8) | fb2; break; }
            cum += (int)hist[fb2];
        }
        s_T = T;
    }
    __syncthreads();
    unsigned T = (unsigned)s_T;
    for (int f = t; f < FF; f += 256) {
        float s = 0.f;
        for (int d = 0; d < DD; d++) s += xs[d] * bf2f(Bp[pan_off(f, d)]);
        ushort k = sortkey(f2bf(s + lb[f]));
        if (k >= T) {
            int p = atomicAdd(&s_pos, 1);
            if (p < RUNC) ridx[(size_t)b * RUNC + p] = f;
        }
    }
    __syncthreads();
    if (t == 0) runcnt[b] = s_pos < RUNC ? s_pos : RUNC;
}

// ---------------- refine: fp64 re-dot of candidates, exact top-32 ----------------
__global__ __launch_bounds__(256) void refine_k(const float* __restrict__ x,
                                                const float* __restrict__ pb,
                                                const float* __restrict__ We,
                                                const float* __restrict__ Wt32,
                                                const float* __restrict__ lb,
                                                const int* __restrict__ runidx,
                                                const int* __restrict__ runcnt,
                                                int use_t,
                                                int* __restrict__ sidx,
                                                float* __restrict__ sval) {
    int b = blockIdx.x, t = threadIdx.x, l = t & 63, w = t >> 6;
    __shared__ float xs[DD];
    __shared__ int ci[RUNC];
    __shared__ float cv[RUNC];
    for (int i = t; i < DD; i += 256) xs[i] = x[(size_t)b * DD + i] - pb[i];
    int c = runcnt[b]; if (c > RUNC) c = RUNC;
    if (t < RUNC) cv[t] = -1e30f;
    if (t < c) ci[t] = runidx[(size_t)b * RUNC + t];
    __syncthreads();
    for (int j = w; j < c; j += 4) {
        int f = ci[j];
        double s = 0.0;
        if (use_t) {
            const float* wr = Wt32 + (size_t)f * DD;
#pragma unroll
            for (int q = 0; q < 12; q++)
                s = fma((double)wr[l + 64 * q], (double)xs[l + 64 * q], s);
        } else {
#pragma unroll
            for (int q = 0; q < 12; q++)
                s = fma((double)We[(size_t)(l + 64 * q) * FF + f], (double)xs[l + 64 * q], s);
        }
#pragma unroll
        for (int o = 32; o >= 1; o >>= 1) s += __shfl_down(s, o);
        if (l == 0) cv[j] = (float)(s + (double)lb[f]);
    }
    __syncthreads();
    if (w == 0) {
        float v0 = (l < RUNC) ? cv[l] : -1e30f;       // FIX: lanes >= RUNC read nothing
        int i0 = (l < c) ? ci[l] : 0x7FFFFFFF;
        for (int sel = 0; sel < TK; sel++) {
            float bv = v0; int bi = i0;
#pragma unroll
            for (int o = 32; o >= 1; o >>= 1) {
                float ov = __shfl_xor(bv, o);
                int oi = __shfl_xor(bi, o);
                if (ov > bv || (ov == bv && oi < bi)) { bv = ov; bi = oi; }
            }
            if (i0 == bi) v0 = -1e30f;
            if (l == 0) {
                if (bi == 0x7FFFFFFF) { bi = 0; bv = -1e30f; }  // FIX: never emit wild index
                sidx[(size_t)b * TK + sel] = bi;
                sval[(size_t)b * TK + sel] = bv > 0.f ? bv : 0.f;
            }
        }
    }
}

// ---------------- decode ----------------
__global__ __launch_bounds__(192) void decode_k(const float* __restrict__ sval,
                                                const int* __restrict__ sidx,
                                                const float* __restrict__ Wd,
                                                const float* __restrict__ pb,
                                                float* __restrict__ out) {
    int b = blockIdx.x, t = threadIdx.x;
    __shared__ float sv[TK];
    __shared__ int si[TK];
    if (t < TK) { sv[t] = sval[(size_t)b * TK + t]; si[t] = sidx[(size_t)b * TK + t]; }
    __syncthreads();
    float4 acc = ((const float4*)pb)[t];
#pragma unroll 4
    for (int j = 0; j < TK; j++) {
        float v = sv[j];
        float4 wv = ((const float4*)(Wd + (size_t)si[j] * DD))[t];
        acc.x += v * wv.x; acc.y += v * wv.y;
        acc.z += v * wv.z; acc.w += v * wv.w;
    }
    ((float4*)out)[(size_t)b * (DD / 4) + t] = acc;
}

extern "C" void kernel_launch(void* const* d_in, const int* in_sizes, int n_in,
                              void* d_out, int out_size, void* d_ws, size_t ws_size,
                              hipStream_t stream) {
    const float* x  = (const float*)d_in[0];
    const float* pb = (const float*)d_in[1];
    const float* We = (const float*)d_in[2];
    const float* lb = (const float*)d_in[3];
    const float* Wd = (const float*)d_in[4];
    float* out = (float*)d_out;
    char* ws = (char*)d_ws;
    (void)in_sizes; (void)n_in; (void)out_size;

    const size_t SZ_AP   = (size_t)NB * DD * 2;              // 12.6 MB
    const size_t SZ_BP   = (size_t)FF * DD * 2;              // 50.3 MB
    const size_t SZ_WT32 = (size_t)FF * DD * 4;              // 100.7 MB
    const size_t SZ_CAND = (size_t)NB * NSEG * SLOT * 4;     // 67.1 MB
    const size_t SZ_TAU  = (size_t)NB * 4;
    const size_t SZ_RIDX = (size_t)NB * RUNC * 4;
    const size_t SZ_RCNT = (size_t)NB * 4;
    const size_t SZ_SIDX = (size_t)NB * TK * 4;
    const size_t SZ_SVAL = (size_t)NB * TK * 4;
    const size_t SZ_CTRL = (size_t)NB * 4 + NS2 * 4 + SZ_CAND;

    size_t need_base = SZ_AP + SZ_BP + SZ_CTRL + (size_t)NB * 4 +
                       SZ_TAU + SZ_RIDX + SZ_RCNT + SZ_SIDX + SZ_SVAL;
    int use_t = (ws_size >= need_base + SZ_WT32) ? 1 : 0;

    size_t off = 0;
    ushort* Ap    = (ushort*)(ws + off); off += SZ_AP;
    ushort* Bp    = (ushort*)(ws + off); off += SZ_BP;
    float*  Wt32  = nullptr;
    if (use_t) { Wt32 = (float*)(ws + off); off += SZ_WT32; }
    char* ctrl0   = (char*)(ws + off);
    unsigned* rowbad = (unsigned*)(ws + off); off += (size_t)NB * 4;
    float* s2part = (float*)(ws + off); off += NS2 * 4;
    unsigned* cand = (unsigned*)(ws + off); off += SZ_CAND;
    size_t ctrl_bytes = (size_t)((ws + off) - ctrl0);
    unsigned* flagv = (unsigned*)(ws + off); off += (size_t)NB * 4;
    float* tau    = (float*)(ws + off); off += SZ_TAU;
    int* ridx     = (int*)(ws + off); off += SZ_RIDX;
    int* rcnt     = (int*)(ws + off); off += SZ_RCNT;
    int* sidx     = (int*)(ws + off); off += SZ_SIDX;
    float* sval   = (float*)(ws + off); off += SZ_SVAL;

    hipMemsetAsync(ctrl0, 0, ctrl_bytes, stream);
    prep_x_k<<<2048, 256, 0, stream>>>(x, pb, Ap);
    prep_w_k<<<dim3(FF / 32, DD / 32), 256, 0, stream>>>(We, Bp, Wt32, s2part);
    rn_k<<<NB / 4, 256, 0, stream>>>(x, pb, s2part, tau);
    gemm_k<<<(NB / 256) * (FF / 256), 512, 0, stream>>>(Ap, Bp, lb, tau, cand, rowbad);
    select2_k<<<NB, 256, 0, stream>>>(cand, rowbad, flagv, ridx, rcnt);
    fb_k<<<NB, 256, 0, stream>>>(flagv, x, pb, Bp, lb, ridx, rcnt);
    refine_k<<<NB, 256, 0, stream>>>(x, pb, We, Wt32, lb, ridx, rcnt, use_t, sidx, sval);
    decode_k<<<NB, 192, 0, stream>>>(sval, sidx, Wd, pb, out);
}

// Round 10
// 1058.893 us; speedup vs baseline: 2.4653x; 1.0492x over previous
//
#include <hip/hip_runtime.h>
#include <stdint.h>

#define GAS __attribute__((address_space(1)))
#define LAS __attribute__((address_space(3)))

typedef __attribute__((ext_vector_type(8))) short bf16x8;
typedef __attribute__((ext_vector_type(4))) float f32x4;

static constexpr int NB = 8192;    // batch
static constexpr int DD = 768;     // model dim (K)
static constexpr int FF = 32768;   // latent dim (N)
static constexpr int TK = 32;      // top-k
static constexpr int RUNC = 48;    // refined candidate cap per row
static constexpr int SLOT = 8;     // survivor slots per (row, 128-col segment)
static constexpr int NSEG = FF / 128;  // 256 segments per row
static constexpr int SORTN = 1024; // select2 sort size
static constexpr int NS2 = 256;    // partial-sum slots for mean(W^2)
static constexpr int NKT = DD / 32;    // 24 K-tiles of 32
static constexpr int PQ = 128 * 32;    // panel elements per K-tile (4096 = 8 KB)

__device__ __forceinline__ ushort f2bf(float f) {
    unsigned x = __float_as_uint(f);
    unsigned r = (x + 0x7FFFu + ((x >> 16) & 1u)) >> 16;
    return (ushort)r;
}
__device__ __forceinline__ ushort sortkey(ushort u) {
    return (u & 0x8000u) ? (ushort)(u ^ 0xFFFFu) : (ushort)(u | 0x8000u);
}
__device__ __forceinline__ float bf2f(ushort u) {
    return __uint_as_float(((unsigned)u) << 16);
}
__device__ __forceinline__ void gload_lds16(const void* g, void* l) {
    __builtin_amdgcn_global_load_lds((const GAS unsigned int*)g,
                                     (LAS unsigned int*)l, 16, 0, 0);
}
// panel element offset: [vtile=v>>7][kt=d>>5][v&127][d&31]
__device__ __forceinline__ size_t pan_off(int v, int d) {
    return ((size_t)(v >> 7) * NKT + (d >> 5)) * PQ + ((v & 127) << 5) + (d & 31);
}

// ---------------- prep: A panels = bf16(x - pre_bias), plain-packed ----------------
__global__ __launch_bounds__(256) void prep_x_k(const float* __restrict__ x,
                                                const float* __restrict__ pb,
                                                ushort* __restrict__ Ap) {
    const int n4 = NB * DD / 4;
    for (int i = blockIdx.x * 256 + threadIdx.x; i < n4; i += gridDim.x * 256) {
        int b = i / (DD / 4), dq = (i % (DD / 4)) * 4;
        float4 v = ((const float4*)x)[i];
        float4 p = ((const float4*)pb)[i % (DD / 4)];
        ushort4 o;
        o.x = f2bf(v.x - p.x); o.y = f2bf(v.y - p.y);
        o.z = f2bf(v.z - p.z); o.w = f2bf(v.w - p.w);
        *(ushort4*)(Ap + pan_off(b, dq)) = o;
    }
}

// ------------- prep: W_enc [D,F] -> B panels (bf16, plain-packed) + Wt32 [F,D] + sum(W^2) -------------
__global__ __launch_bounds__(256) void prep_w_k(const float* __restrict__ W,
                                                ushort* __restrict__ Bp,
                                                float* __restrict__ Wt32,
                                                float* __restrict__ s2part) {
    __shared__ float tile[32][33];
    int f0 = blockIdx.x * 32, d0 = blockIdx.y * 32;
    int tx = threadIdx.x & 31, ty = threadIdx.x >> 5;  // ty 0..7
    float ss = 0.f;
#pragma unroll
    for (int q = 0; q < 4; q++) {
        int dl = ty + q * 8;
        float v = W[(size_t)(d0 + dl) * FF + f0 + tx];
        tile[dl][tx] = v;
        ss += v * v;
    }
#pragma unroll
    for (int o = 32; o >= 1; o >>= 1) ss += __shfl_down(ss, o);
    if ((threadIdx.x & 63) == 0) {
        int slot = (blockIdx.x * 97 + blockIdx.y * 13 + (threadIdx.x >> 6)) & (NS2 - 1);
        atomicAdd(&s2part[slot], ss);
    }
    __syncthreads();
#pragma unroll
    for (int q = 0; q < 4; q++) {
        int fl = ty + q * 8;
        float v = tile[tx][fl];
        int f = f0 + fl, d = d0 + tx;
        Bp[pan_off(f, d)] = f2bf(v);
        if (Wt32) Wt32[(size_t)f * DD + d] = v;
    }
}

// ---------------- per-row threshold: tau[b] = 2.5 * sqrt(mean(W^2)) * ||x_b - pb|| ----------------
__global__ __launch_bounds__(256) void rn_k(const float* __restrict__ x,
                                            const float* __restrict__ pb,
                                            const float* __restrict__ s2part,
                                            float* __restrict__ tau) {
    int t = threadIdx.x, l = t & 63, w = t >> 6;
    __shared__ float wsum[4];
    __shared__ float s2m;
    float p = s2part[t];  // NS2 == 256
#pragma unroll
    for (int o = 32; o >= 1; o >>= 1) p += __shfl_down(p, o);
    if (l == 0) wsum[w] = p;
    __syncthreads();
    if (t == 0) s2m = (wsum[0] + wsum[1] + wsum[2] + wsum[3]) / ((float)DD * (float)FF);
    __syncthreads();
    int row = blockIdx.x * 4 + w;
    float ss = 0.f;
#pragma unroll
    for (int q = 0; q < 12; q++) {
        int d = l + 64 * q;
        float v = x[(size_t)row * DD + d] - pb[d];
        ss += v * v;
    }
#pragma unroll
    for (int o = 32; o >= 1; o >>= 1) ss += __shfl_down(ss, o);
    if (l == 0) tau[row] = 2.5f * sqrtf(s2m * ss);
}

// ---------------- 128x128 bf16 MFMA GEMM, ring-3 BK=32, 1 barrier/kt, 3 blocks/CU ----------------
// 4 waves (2M x 2N), per-wave 64x64 out = acc[4][4] of 16x16x32 frags.
// Linear LDS (64-B rows -> uniform 8/bank, conflict-free). Counted vmcnt(4).
// Fused filter epilogue (LDS-buffered append, r7/r9-verified).
__global__ __launch_bounds__(256, 3) void gemm_k(const ushort* __restrict__ Ap,
                                                 const ushort* __restrict__ Bp,
                                                 const float* __restrict__ lbias,
                                                 const float* __restrict__ tau,
                                                 unsigned* __restrict__ cand,
                                                 unsigned* __restrict__ rowbad) {
    __shared__ __align__(16) char smem[49152];   // 3 ring slots x (A 8K + B 8K)

    int bid = (int)blockIdx.x;                   // nwg = 16384, %8==0
    int wg = (bid & 7) * 2048 + (bid >> 3);      // bijective XCD swizzle
    int mt = wg >> 8, nt = wg & 255;             // per XCD: 8 mt stripes, nt-major
    int m0 = mt << 7, n0 = nt << 7;

    int t = threadIdx.x, l = t & 63, w = t >> 6;
    int wm = w >> 1, wn = w & 1;                 // 2M x 2N

    const ushort* sA = Ap + (size_t)mt * NKT * PQ + t * 8;
    const ushort* sB = Bp + (size_t)nt * NKT * PQ + t * 8;
    int ldA = t * 16, ldB = 8192 + t * 16;

    int aro = (wm * 64 + (l & 15)) * 64 + ((l >> 4) << 4);
    int bro = (wn * 64 + (l & 15)) * 64 + ((l >> 4) << 4);

    f32x4 acc[4][4] = {};

#define STAGE(slot, kt)                                                       \
    {                                                                         \
        const size_t o = (size_t)(kt) * PQ;                                   \
        char* base = smem + (slot) * 16384;                                   \
        gload_lds16(sA + o, base + ldA);                                      \
        gload_lds16(sA + o + 2048, base + ldA + 4096);                        \
        gload_lds16(sB + o, base + ldB);                                      \
        gload_lds16(sB + o + 2048, base + ldB + 4096);                        \
    }

    // prologue: stage kt 0,1
    STAGE(0, 0)
    STAGE(1, 1)
    asm volatile("s_waitcnt vmcnt(4)" ::: "memory");   // kt0 landed; kt1 in flight
    __builtin_amdgcn_s_barrier();
    __builtin_amdgcn_sched_barrier(0);

    int cur = 0;
#pragma unroll 1
    for (int kt = 0; kt < NKT; kt++) {
        const char* As = smem + cur * 16384;
        const char* Bs = As + 8192;
        int nxt = cur + 2; if (nxt >= 3) nxt -= 3;     // slot of kt+2 == slot freed at kt-1
        if (kt < NKT - 2) STAGE(nxt, kt + 2)

        bf16x8 af[4], bfr[4];
        af[0]  = *(const bf16x8*)(As + aro);
        af[1]  = *(const bf16x8*)(As + aro + 1024);
        af[2]  = *(const bf16x8*)(As + aro + 2048);
        af[3]  = *(const bf16x8*)(As + aro + 3072);
        bfr[0] = *(const bf16x8*)(Bs + bro);
        bfr[1] = *(const bf16x8*)(Bs + bro + 1024);
        bfr[2] = *(const bf16x8*)(Bs + bro + 2048);
        bfr[3] = *(const bf16x8*)(Bs + bro + 3072);
        asm volatile("s_waitcnt lgkmcnt(0)" ::: "memory");
        __builtin_amdgcn_sched_barrier(0);             // rule #18: fence MFMA behind lgkmcnt
        __builtin_amdgcn_s_setprio(1);
#pragma unroll
        for (int mi = 0; mi < 4; mi++)
#pragma unroll
            for (int ni = 0; ni < 4; ni++)
                acc[mi][ni] = __builtin_amdgcn_mfma_f32_16x16x32_bf16(
                    af[mi], bfr[ni], acc[mi][ni], 0, 0, 0);
        __builtin_amdgcn_s_setprio(0);
        __builtin_amdgcn_sched_barrier(0);
        if (kt < NKT - 2)
            asm volatile("s_waitcnt vmcnt(4)" ::: "memory");  // kt+1's 4 landed; kt+2's may fly
        else
            asm volatile("s_waitcnt vmcnt(0)" ::: "memory");
        __builtin_amdgcn_s_barrier();                  // single barrier per kt
        __builtin_amdgcn_sched_barrier(0);
        cur = cur + 1; if (cur == 3) cur = 0;
    }
#undef STAGE

    // ---- epilogue: C/D map col=lane&15, row=(lane>>4)*4+j; LDS-buffered survivor append ----
    __syncthreads();
    int* lcnt = (int*)smem;                       // [128]
    unsigned* lbuf = (unsigned*)(smem + 512);     // [128][SLOT]
    if (t < 128) lcnt[t] = 0;
    __syncthreads();
    float lbv[4]; int fcol[4];
#pragma unroll
    for (int ni = 0; ni < 4; ni++) {
        fcol[ni] = n0 + wn * 64 + ni * 16 + (l & 15);
        lbv[ni] = lbias[fcol[ni]];
    }
#pragma unroll
    for (int mi = 0; mi < 4; mi++) {
        int rl = wm * 64 + mi * 16 + ((l >> 4) << 2);
        float4 tq = *(const float4*)(tau + m0 + rl);
        float tj[4] = {tq.x, tq.y, tq.z, tq.w};
#pragma unroll
        for (int ni = 0; ni < 4; ni++) {
            f32x4 v4 = acc[mi][ni];
#pragma unroll
            for (int j = 0; j < 4; j++) {
                float v = v4[j] + lbv[ni];
                if (v >= tj[j]) {
                    int idx = rl + j;
                    int p = atomicAdd(&lcnt[idx], 1);
                    if (p < SLOT)
                        lbuf[idx * SLOT + p] =
                            ((unsigned)sortkey(f2bf(v)) << 16) | (unsigned)(32767 - fcol[ni]);
                }
            }
        }
    }
    __syncthreads();
    if (t < 128) {
        int c = lcnt[t];
        int gr = m0 + t;
        if (c > SLOT) { atomicOr(&rowbad[gr], 1u); c = SLOT; }
        unsigned* dstc = cand + (size_t)gr * (NSEG * SLOT) + nt * SLOT;
        for (int s2 = 0; s2 < c; s2++) dstc[s2] = lbuf[t * SLOT + s2];
    }
}

// ---------------- per-row: gather nonzero slots, sort, keep top-RUNC; flag pathological rows ----------------
__global__ __launch_bounds__(256) void select2_k(const unsigned* __restrict__ cand,
                                                 const unsigned* __restrict__ rowbad,
                                                 unsigned* __restrict__ flagv,
                                                 int* __restrict__ ridx,
                                                 int* __restrict__ runcnt) {
    int b = blockIdx.x, t = threadIdx.x;
    __shared__ unsigned srt[SORTN];
    __shared__ int s_cnt;
    for (int i = t; i < SORTN; i += 256) srt[i] = 0;
    if (t == 0) s_cnt = 0;
    __syncthreads();
    const uint4* src = (const uint4*)(cand + (size_t)b * (NSEG * SLOT));
    for (int i = t; i < NSEG * SLOT / 4; i += 256) {
        uint4 v4 = src[i];
        unsigned d[4] = {v4.x, v4.y, v4.z, v4.w};
#pragma unroll
        for (int q = 0; q < 4; q++)
            if (d[q]) {
                int p = atomicAdd(&s_cnt, 1);
                if (p < SORTN) srt[p] = d[q];
            }
    }
    __syncthreads();
    int cnt = s_cnt;
    int bad = (rowbad[b] != 0u) || cnt < 48 || cnt > SORTN;
    if (t == 0) { flagv[b] = bad; if (bad) runcnt[b] = 0; }
    if (bad) return;
    for (int k = 2; k <= SORTN; k <<= 1) {
        for (int j = k >> 1; j > 0; j >>= 1) {
#pragma unroll
            for (int q = 0; q < SORTN / 256; q++) {
                int i = t + q * 256;
                int ixj = i ^ j;
                if (ixj > i) {
                    unsigned a = srt[i], c2 = srt[ixj];
                    bool sw = ((i & k) == 0) ? (a < c2) : (a > c2);
                    if (sw) { srt[i] = c2; srt[ixj] = a; }
                }
            }
            __syncthreads();
        }
    }
    int nc = cnt < RUNC ? cnt : RUNC;
    if (t < nc) ridx[(size_t)b * RUNC + t] = 32767 - (int)(srt[t] & 0xFFFFu);
    if (t == 0) runcnt[b] = nc;
}

// ---------------- exact fallback for flagged rows (expected: zero rows) ----------------
__global__ __launch_bounds__(256) void fb_k(const unsigned* __restrict__ flagv,
                                            const float* __restrict__ x,
                                            const float* __restrict__ pb,
                                            const ushort* __restrict__ Bp,
                                            const float* __restrict__ lb,
                                            int* __restrict__ ridx,
                                            int* __restrict__ runcnt) {
    int b = blockIdx.x;
    if (!flagv[b]) return;
    int t = threadIdx.x;
    __shared__ float xs[DD];
    __shared__ unsigned hist[256];
    __shared__ int s_cb, s_cum, s_T, s_pos;
    for (int i = t; i < DD; i += 256) xs[i] = x[(size_t)b * DD + i] - pb[i];
    hist[t] = 0;
    if (t == 0) s_pos = 0;
    __syncthreads();
    for (int f = t; f < FF; f += 256) {
        float s = 0.f;
        for (int d = 0; d < DD; d++) s += xs[d] * bf2f(Bp[pan_off(f, d)]);
        ushort k = sortkey(f2bf(s + lb[f]));
        atomicAdd(&hist[k >> 8], 1u);
    }
    __syncthreads();
    if (t == 0) {
        int cum = 0, cb2 = 0;
        for (int i = 255; i >= 0; i--) {
            if (cum + (int)hist[i] >= 48) { cb2 = i; break; }
            cum += (int)hist[i];
        }
        s_cb = cb2; s_cum = cum;
    }
    __syncthreads();
    int cb2 = s_cb;
    hist[t] = 0;
    __syncthreads();
    for (int f = t; f < FF; f += 256) {
        float s = 0.f;
        for (int d = 0; d < DD; d++) s += xs[d] * bf2f(Bp[pan_off(f, d)]);
        ushort k = sortkey(f2bf(s + lb[f]));
        if ((int)(k >> 8) == cb2) atomicAdd(&hist[k & 0xFF], 1u);
    }
    __syncthreads();
    if (t == 0) {
        int cum = s_cum, T = cb2 << 8;
        for (int fb2 = 255; fb2 >= 0; fb2--) {
            if (cum + (int)hist[fb2] >= 48) { T = (cb2 << 8) | fb2; break; }
            cum += (int)hist[fb2];
        }
        s_T = T;
    }
    __syncthreads();
    unsigned T = (unsigned)s_T;
    for (int f = t; f < FF; f += 256) {
        float s = 0.f;
        for (int d = 0; d < DD; d++) s += xs[d] * bf2f(Bp[pan_off(f, d)]);
        ushort k = sortkey(f2bf(s + lb[f]));
        if (k >= T) {
            int p = atomicAdd(&s_pos, 1);
            if (p < RUNC) ridx[(size_t)b * RUNC + p] = f;
        }
    }
    __syncthreads();
    if (t == 0) runcnt[b] = s_pos < RUNC ? s_pos : RUNC;
}

// ---------------- refine: fp64 re-dot of candidates, exact top-32 ----------------
__global__ __launch_bounds__(256) void refine_k(const float* __restrict__ x,
                                                const float* __restrict__ pb,
                                                const float* __restrict__ We,
                                                const float* __restrict__ Wt32,
                                                const float* __restrict__ lb,
                                                const int* __restrict__ runidx,
                                                const int* __restrict__ runcnt,
                                                int use_t,
                                                int* __restrict__ sidx,
                                                float* __restrict__ sval) {
    int b = blockIdx.x, t = threadIdx.x, l = t & 63, w = t >> 6;
    __shared__ float xs[DD];
    __shared__ int ci[RUNC];
    __shared__ float cv[RUNC];
    for (int i = t; i < DD; i += 256) xs[i] = x[(size_t)b * DD + i] - pb[i];
    int c = runcnt[b]; if (c > RUNC) c = RUNC;
    if (t < RUNC) cv[t] = -1e30f;
    if (t < c) ci[t] = runidx[(size_t)b * RUNC + t];
    __syncthreads();
    for (int j = w; j < c; j += 4) {
        int f = ci[j];
        double s = 0.0;
        if (use_t) {
            const float* wr = Wt32 + (size_t)f * DD;
#pragma unroll
            for (int q = 0; q < 12; q++)
                s = fma((double)wr[l + 64 * q], (double)xs[l + 64 * q], s);
        } else {
#pragma unroll
            for (int q = 0; q < 12; q++)
                s = fma((double)We[(size_t)(l + 64 * q) * FF + f], (double)xs[l + 64 * q], s);
        }
#pragma unroll
        for (int o = 32; o >= 1; o >>= 1) s += __shfl_down(s, o);
        if (l == 0) cv[j] = (float)(s + (double)lb[f]);
    }
    __syncthreads();
    if (w == 0) {
        float v0 = (l < RUNC) ? cv[l] : -1e30f;
        int i0 = (l < c) ? ci[l] : 0x7FFFFFFF;
        for (int sel = 0; sel < TK; sel++) {
            float bv = v0; int bi = i0;
#pragma unroll
            for (int o = 32; o >= 1; o >>= 1) {
                float ov = __shfl_xor(bv, o);
                int oi = __shfl_xor(bi, o);
                if (ov > bv || (ov == bv && oi < bi)) { bv = ov; bi = oi; }
            }
            if (i0 == bi) v0 = -1e30f;
            if (l == 0) {
                if (bi == 0x7FFFFFFF) { bi = 0; bv = -1e30f; }
                sidx[(size_t)b * TK + sel] = bi;
                sval[(size_t)b * TK + sel] = bv > 0.f ? bv : 0.f;
            }
        }
    }
}

// ---------------- decode ----------------
__global__ __launch_bounds__(192) void decode_k(const float* __restrict__ sval,
                                                const int* __restrict__ sidx,
                                                const float* __restrict__ Wd,
                                                const float* __restrict__ pb,
                                                float* __restrict__ out) {
    int b = blockIdx.x, t = threadIdx.x;
    __shared__ float sv[TK];
    __shared__ int si[TK];
    if (t < TK) { sv[t] = sval[(size_t)b * TK + t]; si[t] = sidx[(size_t)b * TK + t]; }
    __syncthreads();
    float4 acc = ((const float4*)pb)[t];
#pragma unroll 4
    for (int j = 0; j < TK; j++) {
        float v = sv[j];
        float4 wv = ((const float4*)(Wd + (size_t)si[j] * DD))[t];
        acc.x += v * wv.x; acc.y += v * wv.y;
        acc.z += v * wv.z; acc.w += v * wv.w;
    }
    ((float4*)out)[(size_t)b * (DD / 4) + t] = acc;
}

extern "C" void kernel_launch(void* const* d_in, const int* in_sizes, int n_in,
                              void* d_out, int out_size, void* d_ws, size_t ws_size,
                              hipStream_t stream) {
    const float* x  = (const float*)d_in[0];
    const float* pb = (const float*)d_in[1];
    const float* We = (const float*)d_in[2];
    const float* lb = (const float*)d_in[3];
    const float* Wd = (const float*)d_in[4];
    float* out = (float*)d_out;
    char* ws = (char*)d_ws;
    (void)in_sizes; (void)n_in; (void)out_size;

    const size_t SZ_AP   = (size_t)NB * DD * 2;              // 12.6 MB
    const size_t SZ_BP   = (size_t)FF * DD * 2;              // 50.3 MB
    const size_t SZ_WT32 = (size_t)FF * DD * 4;              // 100.7 MB
    const size_t SZ_CAND = (size_t)NB * NSEG * SLOT * 4;     // 67.1 MB
    const size_t SZ_TAU  = (size_t)NB * 4;
    const size_t SZ_RIDX = (size_t)NB * RUNC * 4;
    const size_t SZ_RCNT = (size_t)NB * 4;
    const size_t SZ_SIDX = (size_t)NB * TK * 4;
    const size_t SZ_SVAL = (size_t)NB * TK * 4;
    const size_t SZ_CTRL = (size_t)NB * 4 + NS2 * 4 + SZ_CAND;

    size_t need_base = SZ_AP + SZ_BP + SZ_CTRL + (size_t)NB * 4 +
                       SZ_TAU + SZ_RIDX + SZ_RCNT + SZ_SIDX + SZ_SVAL;
    int use_t = (ws_size >= need_base + SZ_WT32) ? 1 : 0;

    size_t off = 0;
    ushort* Ap    = (ushort*)(ws + off); off += SZ_AP;
    ushort* Bp    = (ushort*)(ws + off); off += SZ_BP;
    float*  Wt32  = nullptr;
    if (use_t) { Wt32 = (float*)(ws + off); off += SZ_WT32; }
    char* ctrl0   = (char*)(ws + off);
    unsigned* rowbad = (unsigned*)(ws + off); off += (size_t)NB * 4;
    float* s2part = (float*)(ws + off); off += NS2 * 4;
    unsigned* cand = (unsigned*)(ws + off); off += SZ_CAND;
    size_t ctrl_bytes = (size_t)((ws + off) - ctrl0);
    unsigned* flagv = (unsigned*)(ws + off); off += (size_t)NB * 4;
    float* tau    = (float*)(ws + off); off += SZ_TAU;
    int* ridx     = (int*)(ws + off); off += SZ_RIDX;
    int* rcnt     = (int*)(ws + off); off += SZ_RCNT;
    int* sidx     = (int*)(ws + off); off += SZ_SIDX;
    float* sval   = (float*)(ws + off); off += SZ_SVAL;

    hipMemsetAsync(ctrl0, 0, ctrl_bytes, stream);
    prep_x_k<<<2048, 256, 0, stream>>>(x, pb, Ap);
    prep_w_k<<<dim3(FF / 32, DD / 32), 256, 0, stream>>>(We, Bp, Wt32, s2part);
    rn_k<<<NB / 4, 256, 0, stream>>>(x, pb, s2part, tau);
    gemm_k<<<(NB / 128) * (FF / 128), 256, 0, stream>>>(Ap, Bp, lb, tau, cand, rowbad);
    select2_k<<<NB, 256, 0, stream>>>(cand, rowbad, flagv, ridx, rcnt);
    fb_k<<<NB, 256, 0, stream>>>(flagv, x, pb, Bp, lb, ridx, rcnt);
    refine_k<<<NB, 256, 0, stream>>>(x, pb, We, Wt32, lb, ridx, rcnt, use_t, sidx, sval);
    decode_k<<<NB, 192, 0, stream>>>(sval, sidx, Wd, pb, out);
}